// Round 9
// baseline (188.771 us; speedup 1.0000x reference)
//
#include <hip/hip_runtime.h>
#include <hip/hip_fp16.h>
#include <type_traits>

#define DIM   160
#define DIM2  25600
#define TY    32
#define TX    32
#define TZ    16
#define HY    38            // TY + 6
#define HX    38            // TX + 6
#define SS    51            // LDS row stride (bank-verified on HW, R7)
#define NSL   22            // TZ + 6
#define NSITE (HY * HX)     // 1444
#define NVOX_D 16384000.0

#define W0 0.03663285f
#define W1 0.11128076f
#define W2 0.21674532f
#define W3 0.27068213f

__global__ void ssim_zero_acc(double* acc) {
    if (threadIdx.x == 0 && blockIdx.x == 0) acc[0] = 0.0;
}

__global__ __launch_bounds__(256, 4) void ssim_main(const float* __restrict__ P,
                                                    const float* __restrict__ T,
                                                    double* __restrict__ acc) {
    const float Wf[7] = {W0, W1, W2, W3, W2, W1, W0};
    const __half2 wh[7] = {__float2half2_rn(W0), __float2half2_rn(W1),
                           __float2half2_rn(W2), __float2half2_rn(W3),
                           __float2half2_rn(W2), __float2half2_rn(W1),
                           __float2half2_rn(W0)};

    __shared__ __half2 sIn[HY * SS];    // (p,t) packed, single buffer
    __shared__ __half2 ycMu[TY * SS];   // (yconv p, yconv t)
    __shared__ __half2 ycE2[TY * SS];   // (yconv p^2, yconv t^2)
    __shared__ __half  ycPt[TY * SS];   // yconv p*t (b16)
    __shared__ float   red[4];

    const int tid = threadIdx.x;
    int bid = blockIdx.x;
    int b  = bid / 250;  int r  = bid - b * 250;   // 10 zc * 5 ty * 5 tx
    int zc = r / 25;     int r2 = r - zc * 25;
    int ty = r2 / 5;     int tx = r2 - ty * 5;

    const int base = b * (DIM * DIM * DIM);
    const int z0 = zc * TZ, y0 = ty * TY - 3, x0 = tx * TX - 3;

    // ---- hoisted staging sites (u = tid + 256k, k<6; 1444 = 5*256 + 164) ----
    int gofs[6], lofs[6];
    bool ld[6], st[6];
#pragma unroll
    for (int k = 0; k < 6; ++k) {
        int u = tid + 256 * k;
        st[k] = (u < NSITE);
        int y = u / HX, x = u - y * HX;
        int gy = y0 + y, gx = x0 + x;
        ld[k] = st[k] & ((unsigned)gy < (unsigned)DIM) & ((unsigned)gx < (unsigned)DIM);
        gofs[k] = gy * DIM + gx;
        lofs[k] = y * SS + x;
    }

    // ---- y-conv pair-task bases ----
    int yb[3];
#pragma unroll
    for (int q = 0; q < 3; ++q) {
        int t = tid + 256 * q; if (t > 607) t = 607;
        int yy = t / HX, x = t - yy * HX;
        yb[q] = (2 * yy) * SS + x;
    }

    // ---- x-conv: row cy = tid>>3, quad xq = tid&7 -> 4 voxels ----
    const int xrd = (tid >> 3) * SS + 4 * (tid & 7);

    const __half2 hz = __float2half2_rn(0.f);
    __half2 azMu[4][7], azE2[4][7], azPtA[7], azPtB[7];
#pragma unroll
    for (int o = 0; o < 4; ++o)
#pragma unroll
        for (int j = 0; j < 7; ++j) { azMu[o][j] = hz; azE2[o][j] = hz; }
#pragma unroll
    for (int j = 0; j < 7; ++j) { azPtA[j] = hz; azPtB[j] = hz; }

    float lsum = 0.f;

    auto ytask = [&](int ybase) {
        __half2 mu0 = hz, mu1 = hz, e20 = hz, e21 = hz;
        float pt0 = 0.f, pt1 = 0.f;
#pragma unroll
        for (int k = 0; k < 8; ++k) {
            __half2 v  = sIn[ybase + k * SS];
            __half2 v2 = __hmul2(v, v);
            __half2 vs = __halves2half2(__high2half(v), __low2half(v));
            float ptf  = __low2float(__hmul2(v, vs));
            if (k < 7) {
                mu0 = __hfma2(wh[k], v, mu0);
                e20 = __hfma2(wh[k], v2, e20);
                pt0 = fmaf(Wf[k], ptf, pt0);
            }
            if (k >= 1) {
                mu1 = __hfma2(wh[k - 1], v, mu1);
                e21 = __hfma2(wh[k - 1], v2, e21);
                pt1 = fmaf(Wf[k - 1], ptf, pt1);
            }
        }
        ycMu[ybase] = mu0; ycMu[ybase + SS] = mu1;
        ycE2[ybase] = e20; ycE2[ybase + SS] = e21;
        ycPt[ybase] = __float2half(pt0); ycPt[ybase + SS] = __float2half(pt1);
    };

    // ---- prologue: stage slice zs = z0-3 ----
    {
        int zs = z0 - 3;
        bool zok = (unsigned)zs < (unsigned)DIM;
        const float* Pp = P + base + zs * DIM2;
        const float* Tp = T + base + zs * DIM2;
        float rp[6], rt[6];
#pragma unroll
        for (int k = 0; k < 6; ++k) {
            rp[k] = 0.f; rt[k] = 0.f;
            if (zok && ld[k]) { rp[k] = Pp[gofs[k]]; rt[k] = Tp[gofs[k]]; }
        }
#pragma unroll
        for (int k = 0; k < 6; ++k)
            if (st[k]) sIn[lofs[k]] = __floats2half2_rn(rp[k], rt[k]);
    }
    __syncthreads();

    // ---- slice body: compile-time rotation phase PH = i % 7 ----
    auto body = [&](auto phc, int i) {
        constexpr int PH = decltype(phc)::value;
        const bool hn = (i + 1 < NSL);
        float rp[6], rt[6];

        if (hn) {
            int zs = z0 + i - 2;
            bool zok = (unsigned)zs < (unsigned)DIM;
            const float* Pp = P + base + zs * DIM2;
            const float* Tp = T + base + zs * DIM2;
#pragma unroll
            for (int k = 0; k < 6; ++k) {
                rp[k] = 0.f; rt[k] = 0.f;
                if (zok && ld[k]) { rp[k] = Pp[gofs[k]]; rt[k] = Tp[gofs[k]]; }
            }
        }

        // phase A: y-conv (608 pair tasks)
        ytask(yb[0]);
        ytask(yb[1]);
        if (tid < 96) ytask(yb[2]);
        __syncthreads();

        // phase B: x-conv (4 outputs/thread, all b32/b16 reads)
        __half2 muw[10], e2w[10]; float ptw[10];
#pragma unroll
        for (int m = 0; m < 10; ++m) {
            muw[m] = ycMu[xrd + m];
            e2w[m] = ycE2[xrd + m];
            ptw[m] = __half2float(ycPt[xrd + m]);
        }
        __half2 xmu[4], xe2[4]; float xpt[4];
#pragma unroll
        for (int o = 0; o < 4; ++o) {
            __half2 am = hz, ae = hz; float ap = 0.f;
#pragma unroll
            for (int k = 0; k < 7; ++k) {
                am = __hfma2(wh[k], muw[o + k], am);
                ae = __hfma2(wh[k], e2w[o + k], ae);
                ap = fmaf(Wf[k], ptw[o + k], ap);
            }
            xmu[o] = am; xe2[o] = ae; xpt[o] = ap;
        }

        // z scatter into rotated slots (all indices compile-time)
        __half2 ptA = __floats2half2_rn(xpt[0], xpt[1]);
        __half2 ptB = __floats2half2_rn(xpt[2], xpt[3]);
#pragma unroll
        for (int j = 0; j < 7; ++j) {
            constexpr int JS[7] = {0, 1, 2, 3, 4, 5, 6};
            const int s = (JS[j] + PH) % 7;   // folds to constant under unroll
            __half2 w2 = wh[6 - j];
#pragma unroll
            for (int o = 0; o < 4; ++o) {
                azMu[o][s] = __hfma2(w2, xmu[o], azMu[o][s]);
                azE2[o][s] = __hfma2(w2, xe2[o], azE2[o][s]);
            }
            azPtA[s] = __hfma2(w2, ptA, azPtA[s]);
            azPtB[s] = __hfma2(w2, ptB, azPtB[s]);
        }

        // SSIM on completed slot PH
        if (i >= 6) {
            float eptv[4] = {__low2float(azPtA[PH]), __high2float(azPtA[PH]),
                             __low2float(azPtB[PH]), __high2float(azPtB[PH])};
#pragma unroll
            for (int o = 0; o < 4; ++o) {
                float mp = __low2float(azMu[o][PH]), mt = __high2float(azMu[o][PH]);
                float ep2 = __low2float(azE2[o][PH]), et2 = __high2float(azE2[o][PH]);
                float mp2 = mp * mp, mt2 = mt * mt, mpt = mp * mt;
                float num = fmaf(2.f, mpt, 1e-4f) * fmaf(2.f, eptv[o] - mpt, 9e-4f);
                float den = (mp2 + mt2 + 1e-4f) * ((ep2 - mp2) + (et2 - mt2) + 9e-4f);
                lsum += num * __builtin_amdgcn_rcpf(den);
            }
        }

        // retire slot PH (becomes logical slot 6 next slice)
#pragma unroll
        for (int o = 0; o < 4; ++o) { azMu[o][PH] = hz; azE2[o][PH] = hz; }
        azPtA[PH] = hz; azPtB[PH] = hz;

        // commit next slice
        if (hn) {
#pragma unroll
            for (int k = 0; k < 6; ++k)
                if (st[k]) sIn[lofs[k]] = __floats2half2_rn(rp[k], rt[k]);
        }
        __syncthreads();
    };

#pragma unroll 1
    for (int ib = 0; ib < 21; ib += 7) {
        body(std::integral_constant<int, 0>{}, ib + 0);
        body(std::integral_constant<int, 1>{}, ib + 1);
        body(std::integral_constant<int, 2>{}, ib + 2);
        body(std::integral_constant<int, 3>{}, ib + 3);
        body(std::integral_constant<int, 4>{}, ib + 4);
        body(std::integral_constant<int, 5>{}, ib + 5);
        body(std::integral_constant<int, 6>{}, ib + 6);
    }
    body(std::integral_constant<int, 0>{}, 21);   // 21 % 7 == 0

    // ---- block reduction, one f64 atomic ----
#pragma unroll
    for (int off = 32; off > 0; off >>= 1) lsum += __shfl_down(lsum, off);
    if ((tid & 63) == 0) red[tid >> 6] = lsum;
    __syncthreads();
    if (tid == 0) atomicAdd(acc, (double)(red[0] + red[1] + red[2] + red[3]));
}

__global__ void ssim_finalize(const double* __restrict__ acc, float* __restrict__ out) {
    if (threadIdx.x == 0 && blockIdx.x == 0)
        out[0] = 1.f - (float)(acc[0] / NVOX_D);
}

extern "C" void kernel_launch(void* const* d_in, const int* in_sizes, int n_in,
                              void* d_out, int out_size, void* d_ws, size_t ws_size,
                              hipStream_t stream) {
    const float* P = (const float*)d_in[0];
    const float* T = (const float*)d_in[1];
    float* out = (float*)d_out;
    double* acc = (double*)d_ws;

    ssim_zero_acc<<<1, 64, 0, stream>>>(acc);
    ssim_main<<<4 * 10 * 5 * 5, 256, 0, stream>>>(P, T, acc);
    ssim_finalize<<<1, 64, 0, stream>>>(acc, out);
}

// Round 10
// 144.823 us; speedup vs baseline: 1.3035x; 1.3035x over previous
//
#include <hip/hip_runtime.h>
#include <hip/hip_fp16.h>

#define DIM   160
#define DIM2  25600
#define TY    32
#define TX    32
#define TZ    16
#define HY    38            // TY + 6
#define HX    38            // TX + 6
#define SS    51            // LDS row stride (bank-verified on HW, R7)
#define NSL   22            // TZ + 6
#define NSITE (HY * HX)     // 1444
#define NVOX_D 16384000.0

#define W0 0.03663285f
#define W1 0.11128076f
#define W2 0.21674532f
#define W3 0.27068213f

__global__ void ssim_zero_acc(double* acc) {
    if (threadIdx.x == 0 && blockIdx.x == 0) acc[0] = 0.0;
}

__global__ __launch_bounds__(256, 4) void ssim_main(const float* __restrict__ P,
                                                    const float* __restrict__ T,
                                                    double* __restrict__ acc) {
    const float Wf[7] = {W0, W1, W2, W3, W2, W1, W0};
    const __half2 wh[7] = {__float2half2_rn(W0), __float2half2_rn(W1),
                           __float2half2_rn(W2), __float2half2_rn(W3),
                           __float2half2_rn(W2), __float2half2_rn(W1),
                           __float2half2_rn(W0)};

    __shared__ __half2 sIn[HY * SS];    // (p,t) packed, single buffer
    __shared__ __half2 ycMu[TY * SS];   // (yconv p, yconv t)
    __shared__ __half2 ycE2[TY * SS];   // (yconv p^2, yconv t^2)
    __shared__ __half  ycPt[TY * SS];   // yconv p*t (b16)
    __shared__ float   red[4];

    const int tid = threadIdx.x;
    int bid = blockIdx.x;
    int b  = bid / 250;  int r  = bid - b * 250;   // 10 zc * 5 ty * 5 tx
    int zc = r / 25;     int r2 = r - zc * 25;
    int ty = r2 / 5;     int tx = r2 - ty * 5;

    const int base = b * (DIM * DIM * DIM);
    const int z0 = zc * TZ, y0 = ty * TY - 3, x0 = tx * TX - 3;

    // ---- hoisted staging sites (u = tid + 256k, k<6; 1444 = 5*256 + 164) ----
    int gofs[6], lofs[6];
    bool ld[6], st[6];
#pragma unroll
    for (int k = 0; k < 6; ++k) {
        int u = tid + 256 * k;
        st[k] = (u < NSITE);
        int y = u / HX, x = u - y * HX;
        int gy = y0 + y, gx = x0 + x;
        ld[k] = st[k] & ((unsigned)gy < (unsigned)DIM) & ((unsigned)gx < (unsigned)DIM);
        gofs[k] = gy * DIM + gx;
        lofs[k] = y * SS + x;
    }

    // ---- y-conv pair-task bases ----
    int yb[3];
#pragma unroll
    for (int q = 0; q < 3; ++q) {
        int t = tid + 256 * q; if (t > 607) t = 607;
        int yy = t / HX, x = t - yy * HX;
        yb[q] = (2 * yy) * SS + x;
    }

    // ---- x-conv: row cy = tid>>3, quad xq = tid&7 -> 4 voxels ----
    const int xrd = (tid >> 3) * SS + 4 * (tid & 7);

    const __half2 hz = __float2half2_rn(0.f);
    __half2 azMu[4][7], azE2[4][7], azPtA[7], azPtB[7];
#pragma unroll
    for (int o = 0; o < 4; ++o)
#pragma unroll
        for (int j = 0; j < 7; ++j) { azMu[o][j] = hz; azE2[o][j] = hz; }
#pragma unroll
    for (int j = 0; j < 7; ++j) { azPtA[j] = hz; azPtB[j] = hz; }

    float lsum = 0.f;

    // y-conv vertical pair: reads 8 packed taps, writes 2 rows x 3 arrays
    auto ytask = [&](int ybase) {
        __half2 mu0 = hz, mu1 = hz, e20 = hz, e21 = hz;
        float pt0 = 0.f, pt1 = 0.f;
#pragma unroll
        for (int k = 0; k < 8; ++k) {
            __half2 v  = sIn[ybase + k * SS];
            __half2 v2 = __hmul2(v, v);
            __half2 vs = __halves2half2(__high2half(v), __low2half(v));
            float ptf  = __low2float(__hmul2(v, vs));
            if (k < 7) {
                mu0 = __hfma2(wh[k], v, mu0);
                e20 = __hfma2(wh[k], v2, e20);
                pt0 = fmaf(Wf[k], ptf, pt0);
            }
            if (k >= 1) {
                mu1 = __hfma2(wh[k - 1], v, mu1);
                e21 = __hfma2(wh[k - 1], v2, e21);
                pt1 = fmaf(Wf[k - 1], ptf, pt1);
            }
        }
        ycMu[ybase] = mu0; ycMu[ybase + SS] = mu1;
        ycE2[ybase] = e20; ycE2[ybase + SS] = e21;
        ycPt[ybase] = __float2half(pt0); ycPt[ybase + SS] = __float2half(pt1);
    };

    // ---- prologue: stage slice zs = z0-3 ----
    {
        int zs = z0 - 3;
        bool zok = (unsigned)zs < (unsigned)DIM;
        const float* Pp = P + base + zs * DIM2;
        const float* Tp = T + base + zs * DIM2;
        float rp[6], rt[6];
#pragma unroll
        for (int k = 0; k < 6; ++k) {
            rp[k] = 0.f; rt[k] = 0.f;
            if (zok && ld[k]) { rp[k] = Pp[gofs[k]]; rt[k] = Tp[gofs[k]]; }
        }
#pragma unroll
        for (int k = 0; k < 6; ++k)
            if (st[k]) sIn[lofs[k]] = __floats2half2_rn(rp[k], rt[k]);
    }
    __syncthreads();

    for (int i = 0; i < NSL; ++i) {
        const bool hn = (i + 1 < NSL);
        float rp[6], rt[6];

        // ---- prefetch next slice into regs (hides HBM under y-conv) ----
        if (hn) {
            int zs = z0 + i - 2;
            bool zok = (unsigned)zs < (unsigned)DIM;
            const float* Pp = P + base + zs * DIM2;
            const float* Tp = T + base + zs * DIM2;
#pragma unroll
            for (int k = 0; k < 6; ++k) {
                rp[k] = 0.f; rt[k] = 0.f;
                if (zok && ld[k]) { rp[k] = Pp[gofs[k]]; rt[k] = Tp[gofs[k]]; }
            }
        }

        // ---- phase A: y-conv (608 pair tasks on 256 threads) ----
        ytask(yb[0]);
        ytask(yb[1]);
        if (tid < 96) ytask(yb[2]);
        __syncthreads();

        // ---- phase B: x-conv (4 outputs/thread, all b32/b16 reads) ----
        __half2 muw[10], e2w[10]; float ptw[10];
#pragma unroll
        for (int m = 0; m < 10; ++m) {
            muw[m] = ycMu[xrd + m];
            e2w[m] = ycE2[xrd + m];
            ptw[m] = __half2float(ycPt[xrd + m]);
        }
        __half2 xmu[4], xe2[4]; float xpt[4];
#pragma unroll
        for (int o = 0; o < 4; ++o) {
            __half2 am = hz, ae = hz; float ap = 0.f;
#pragma unroll
            for (int k = 0; k < 7; ++k) {
                am = __hfma2(wh[k], muw[o + k], am);
                ae = __hfma2(wh[k], e2w[o + k], ae);
                ap = fmaf(Wf[k], ptw[o + k], ap);
            }
            xmu[o] = am; xe2[o] = ae; xpt[o] = ap;
        }

        // ---- z scatter ----
        __half2 ptA = __floats2half2_rn(xpt[0], xpt[1]);
        __half2 ptB = __floats2half2_rn(xpt[2], xpt[3]);
#pragma unroll
        for (int j = 0; j < 7; ++j) {
            __half2 w2 = wh[6 - j];
#pragma unroll
            for (int o = 0; o < 4; ++o) {
                azMu[o][j] = __hfma2(w2, xmu[o], azMu[o][j]);
                azE2[o][j] = __hfma2(w2, xe2[o], azE2[o][j]);
            }
            azPtA[j] = __hfma2(w2, ptA, azPtA[j]);
            azPtB[j] = __hfma2(w2, ptB, azPtB[j]);
        }

        // ---- SSIM on completed slot 0 ----
        if (i >= 6) {
            float eptv[4] = {__low2float(azPtA[0]), __high2float(azPtA[0]),
                             __low2float(azPtB[0]), __high2float(azPtB[0])};
#pragma unroll
            for (int o = 0; o < 4; ++o) {
                float mp = __low2float(azMu[o][0]), mt = __high2float(azMu[o][0]);
                float ep2 = __low2float(azE2[o][0]), et2 = __high2float(azE2[o][0]);
                float mp2 = mp * mp, mt2 = mt * mt, mpt = mp * mt;
                float num = fmaf(2.f, mpt, 1e-4f) * fmaf(2.f, eptv[o] - mpt, 9e-4f);
                float den = (mp2 + mt2 + 1e-4f) * ((ep2 - mp2) + (et2 - mt2) + 9e-4f);
                lsum += num * __builtin_amdgcn_rcpf(den);
            }
        }

        // ---- shift z pipes ----
#pragma unroll
        for (int j = 0; j < 6; ++j) {
#pragma unroll
            for (int o = 0; o < 4; ++o) {
                azMu[o][j] = azMu[o][j + 1];
                azE2[o][j] = azE2[o][j + 1];
            }
            azPtA[j] = azPtA[j + 1];
            azPtB[j] = azPtB[j + 1];
        }
#pragma unroll
        for (int o = 0; o < 4; ++o) { azMu[o][6] = hz; azE2[o][6] = hz; }
        azPtA[6] = hz; azPtB[6] = hz;

        // ---- commit next slice (b32 packed writes) ----
        if (hn) {
#pragma unroll
            for (int k = 0; k < 6; ++k)
                if (st[k]) sIn[lofs[k]] = __floats2half2_rn(rp[k], rt[k]);
        }
        __syncthreads();
    }

    // ---- block reduction, one f64 atomic ----
#pragma unroll
    for (int off = 32; off > 0; off >>= 1) lsum += __shfl_down(lsum, off);
    if ((tid & 63) == 0) red[tid >> 6] = lsum;
    __syncthreads();
    if (tid == 0) atomicAdd(acc, (double)(red[0] + red[1] + red[2] + red[3]));
}

__global__ void ssim_finalize(const double* __restrict__ acc, float* __restrict__ out) {
    if (threadIdx.x == 0 && blockIdx.x == 0)
        out[0] = 1.f - (float)(acc[0] / NVOX_D);
}

extern "C" void kernel_launch(void* const* d_in, const int* in_sizes, int n_in,
                              void* d_out, int out_size, void* d_ws, size_t ws_size,
                              hipStream_t stream) {
    const float* P = (const float*)d_in[0];
    const float* T = (const float*)d_in[1];
    float* out = (float*)d_out;
    double* acc = (double*)d_ws;

    ssim_zero_acc<<<1, 64, 0, stream>>>(acc);
    ssim_main<<<4 * 10 * 5 * 5, 256, 0, stream>>>(P, T, acc);
    ssim_finalize<<<1, 64, 0, stream>>>(acc, out);
}

// Round 11
// 103.222 us; speedup vs baseline: 1.8288x; 1.4030x over previous
//
#include <hip/hip_runtime.h>
#include <hip/hip_fp16.h>

#define DIM   160
#define DIM2  25600
#define TY    32
#define TX    32
#define TZ    16
#define HY    38            // TY + 6
#define HX    38            // TX + 6
#define SS    51            // sIn row stride (bank-verified on HW, R7)
#define YSTR  39            // yc row stride (odd; bijection-verified banks)
#define YCH   (TY * YSTR)
#define NSL   22            // TZ + 6
#define NSITE (HY * HX)     // 1444
#define NVOX_D 16384000.0

#define W0 0.03663285f
#define W1 0.11128076f
#define W2 0.21674532f
#define W3 0.27068213f

__global__ void ssim_zero_acc(double* acc) {
    if (threadIdx.x == 0 && blockIdx.x == 0) acc[0] = 0.0;
}

__global__ __launch_bounds__(256, 3) void ssim_main(const float* __restrict__ P,
                                                    const float* __restrict__ T,
                                                    double* __restrict__ acc) {
    const float Wf[7] = {W0, W1, W2, W3, W2, W1, W0};
    const __half2 wh[7] = {__float2half2_rn(W0), __float2half2_rn(W1),
                           __float2half2_rn(W2), __float2half2_rn(W3),
                           __float2half2_rn(W2), __float2half2_rn(W1),
                           __float2half2_rn(W0)};

    __shared__ __half2 sIn[HY * SS];    // (p,t) packed, single buffer, stride 51
    __shared__ __half2 ycMu[YCH];       // (yconv p, yconv t), stride 39
    __shared__ __half2 ycE2[YCH];       // (yconv p^2, yconv t^2), stride 39
    __shared__ float   ycPt[YCH];       // yconv p*t (f32), stride 39
    __shared__ float   red[4];

    const int tid = threadIdx.x;
    int bid = blockIdx.x;
    int b  = bid / 250;  int r  = bid - b * 250;   // 10 zc * 5 ty * 5 tx
    int zc = r / 25;     int r2 = r - zc * 25;
    int ty = r2 / 5;     int tx = r2 - ty * 5;

    const int base = b * (DIM * DIM * DIM);
    const int z0 = zc * TZ, y0 = ty * TY - 3, x0 = tx * TX - 3;

    // ---- hoisted staging sites (u = tid + 256k, k<6; 1444 = 5*256 + 164) ----
    int gofs[6], lofs[6];
    bool ld[6], st[6];
#pragma unroll
    for (int k = 0; k < 6; ++k) {
        int u = tid + 256 * k;
        st[k] = (u < NSITE);
        int y = u / HX, x = u - y * HX;
        int gy = y0 + y, gx = x0 + x;
        ld[k] = st[k] & ((unsigned)gy < (unsigned)DIM) & ((unsigned)gx < (unsigned)DIM);
        gofs[k] = gy * DIM + gx;
        lofs[k] = y * SS + x;
    }

    // ---- y-conv pair-task bases: read base (sIn, 51), write base (yc, 39) ----
    int ybR[3], ybW[3];
#pragma unroll
    for (int q = 0; q < 3; ++q) {
        int t = tid + 256 * q; if (t > 607) t = 607;
        int yy = t / HX, x = t - yy * HX;
        ybR[q] = (2 * yy) * SS + x;
        ybW[q] = (2 * yy) * YSTR + x;
    }

    // ---- x-conv: row cy = tid>>3, quad xq = tid&7 -> 4 voxels ----
    const int xrd = (tid >> 3) * YSTR + 4 * (tid & 7);

    const __half2 hz = __float2half2_rn(0.f);
    __half2 azMu[4][7], azE2[4][7], azPtA[7], azPtB[7];
#pragma unroll
    for (int o = 0; o < 4; ++o)
#pragma unroll
        for (int j = 0; j < 7; ++j) { azMu[o][j] = hz; azE2[o][j] = hz; }
#pragma unroll
    for (int j = 0; j < 7; ++j) { azPtA[j] = hz; azPtB[j] = hz; }

    float lsum = 0.f;

    // y-conv vertical pair: reads 8 packed taps (stride 51), writes 2 rows x 3 arrays (stride 39)
    auto ytask = [&](int rb, int wb) {
        __half2 mu0 = hz, mu1 = hz, e20 = hz, e21 = hz;
        float pt0 = 0.f, pt1 = 0.f;
#pragma unroll
        for (int k = 0; k < 8; ++k) {
            __half2 v  = sIn[rb + k * SS];
            __half2 v2 = __hmul2(v, v);
            __half2 vs = __halves2half2(__high2half(v), __low2half(v));
            float ptf  = __low2float(__hmul2(v, vs));
            if (k < 7) {
                mu0 = __hfma2(wh[k], v, mu0);
                e20 = __hfma2(wh[k], v2, e20);
                pt0 = fmaf(Wf[k], ptf, pt0);
            }
            if (k >= 1) {
                mu1 = __hfma2(wh[k - 1], v, mu1);
                e21 = __hfma2(wh[k - 1], v2, e21);
                pt1 = fmaf(Wf[k - 1], ptf, pt1);
            }
        }
        ycMu[wb] = mu0; ycMu[wb + YSTR] = mu1;
        ycE2[wb] = e20; ycE2[wb + YSTR] = e21;
        ycPt[wb] = pt0; ycPt[wb + YSTR] = pt1;
    };

    // ---- prologue: stage slice zs = z0-3 ----
    {
        int zs = z0 - 3;
        bool zok = (unsigned)zs < (unsigned)DIM;
        const float* Pp = P + base + zs * DIM2;
        const float* Tp = T + base + zs * DIM2;
        float rp[6], rt[6];
#pragma unroll
        for (int k = 0; k < 6; ++k) {
            rp[k] = 0.f; rt[k] = 0.f;
            if (zok && ld[k]) { rp[k] = Pp[gofs[k]]; rt[k] = Tp[gofs[k]]; }
        }
#pragma unroll
        for (int k = 0; k < 6; ++k)
            if (st[k]) sIn[lofs[k]] = __floats2half2_rn(rp[k], rt[k]);
    }
    __syncthreads();

    for (int i = 0; i < NSL; ++i) {
        const bool hn = (i + 1 < NSL);
        float rp[6], rt[6];

        // ---- prefetch next slice into regs (hides HBM under y-conv) ----
        if (hn) {
            int zs = z0 + i - 2;
            bool zok = (unsigned)zs < (unsigned)DIM;
            const float* Pp = P + base + zs * DIM2;
            const float* Tp = T + base + zs * DIM2;
#pragma unroll
            for (int k = 0; k < 6; ++k) {
                rp[k] = 0.f; rt[k] = 0.f;
                if (zok && ld[k]) { rp[k] = Pp[gofs[k]]; rt[k] = Tp[gofs[k]]; }
            }
        }

        // ---- phase A: y-conv (608 pair tasks on 256 threads) ----
        ytask(ybR[0], ybW[0]);
        ytask(ybR[1], ybW[1]);
        if (tid < 96) ytask(ybR[2], ybW[2]);
        __syncthreads();

        // ---- phase B: x-conv (4 outputs/thread, all b32 reads) ----
        __half2 muw[10], e2w[10]; float ptw[10];
#pragma unroll
        for (int m = 0; m < 10; ++m) {
            muw[m] = ycMu[xrd + m];
            e2w[m] = ycE2[xrd + m];
            ptw[m] = ycPt[xrd + m];
        }
        __half2 xmu[4], xe2[4]; float xpt[4];
#pragma unroll
        for (int o = 0; o < 4; ++o) {
            __half2 am = hz, ae = hz; float ap = 0.f;
#pragma unroll
            for (int k = 0; k < 7; ++k) {
                am = __hfma2(wh[k], muw[o + k], am);
                ae = __hfma2(wh[k], e2w[o + k], ae);
                ap = fmaf(Wf[k], ptw[o + k], ap);
            }
            xmu[o] = am; xe2[o] = ae; xpt[o] = ap;
        }

        // ---- z scatter ----
        __half2 ptA = __floats2half2_rn(xpt[0], xpt[1]);
        __half2 ptB = __floats2half2_rn(xpt[2], xpt[3]);
#pragma unroll
        for (int j = 0; j < 7; ++j) {
            __half2 w2 = wh[6 - j];
#pragma unroll
            for (int o = 0; o < 4; ++o) {
                azMu[o][j] = __hfma2(w2, xmu[o], azMu[o][j]);
                azE2[o][j] = __hfma2(w2, xe2[o], azE2[o][j]);
            }
            azPtA[j] = __hfma2(w2, ptA, azPtA[j]);
            azPtB[j] = __hfma2(w2, ptB, azPtB[j]);
        }

        // ---- SSIM on completed slot 0 ----
        if (i >= 6) {
            float eptv[4] = {__low2float(azPtA[0]), __high2float(azPtA[0]),
                             __low2float(azPtB[0]), __high2float(azPtB[0])};
#pragma unroll
            for (int o = 0; o < 4; ++o) {
                float mp = __low2float(azMu[o][0]), mt = __high2float(azMu[o][0]);
                float ep2 = __low2float(azE2[o][0]), et2 = __high2float(azE2[o][0]);
                float mp2 = mp * mp, mt2 = mt * mt, mpt = mp * mt;
                float num = fmaf(2.f, mpt, 1e-4f) * fmaf(2.f, eptv[o] - mpt, 9e-4f);
                float den = (mp2 + mt2 + 1e-4f) * ((ep2 - mp2) + (et2 - mt2) + 9e-4f);
                lsum += num * __builtin_amdgcn_rcpf(den);
            }
        }

        // ---- shift z pipes ----
#pragma unroll
        for (int j = 0; j < 6; ++j) {
#pragma unroll
            for (int o = 0; o < 4; ++o) {
                azMu[o][j] = azMu[o][j + 1];
                azE2[o][j] = azE2[o][j + 1];
            }
            azPtA[j] = azPtA[j + 1];
            azPtB[j] = azPtB[j + 1];
        }
#pragma unroll
        for (int o = 0; o < 4; ++o) { azMu[o][6] = hz; azE2[o][6] = hz; }
        azPtA[6] = hz; azPtB[6] = hz;

        // ---- commit next slice (b32 packed writes) ----
        if (hn) {
#pragma unroll
            for (int k = 0; k < 6; ++k)
                if (st[k]) sIn[lofs[k]] = __floats2half2_rn(rp[k], rt[k]);
        }
        __syncthreads();
    }

    // ---- block reduction, one f64 atomic ----
#pragma unroll
    for (int off = 32; off > 0; off >>= 1) lsum += __shfl_down(lsum, off);
    if ((tid & 63) == 0) red[tid >> 6] = lsum;
    __syncthreads();
    if (tid == 0) atomicAdd(acc, (double)(red[0] + red[1] + red[2] + red[3]));
}

__global__ void ssim_finalize(const double* __restrict__ acc, float* __restrict__ out) {
    if (threadIdx.x == 0 && blockIdx.x == 0)
        out[0] = 1.f - (float)(acc[0] / NVOX_D);
}

extern "C" void kernel_launch(void* const* d_in, const int* in_sizes, int n_in,
                              void* d_out, int out_size, void* d_ws, size_t ws_size,
                              hipStream_t stream) {
    const float* P = (const float*)d_in[0];
    const float* T = (const float*)d_in[1];
    float* out = (float*)d_out;
    double* acc = (double*)d_ws;

    ssim_zero_acc<<<1, 64, 0, stream>>>(acc);
    ssim_main<<<4 * 10 * 5 * 5, 256, 0, stream>>>(P, T, acc);
    ssim_finalize<<<1, 64, 0, stream>>>(acc, out);
}